// Round 1
// baseline (961.165 us; speedup 1.0000x reference)
//
#include <hip/hip_runtime.h>

// Problem constants (fixed by the reference)
#define N_ROWS 80000
#define DDIM   2049
#define KF     7

constexpr int ROWS_PER_BLK = 64;           // 1 wave per block, 1 row per thread
constexpr int DT           = 32;           // d-chunk width (columns per stage)
constexpr int XSTRIDE      = 36;           // padded LDS row stride in floats (16B aligned, conflict-min)
constexpr int NBLK         = N_ROWS / ROWS_PER_BLK;  // 1250 exactly

// Stage 1: per-row dot products vs all 7 embedding rows, clip with out2,
// write full [7][N] clipped matrix + per-block per-k max partials.
__global__ __launch_bounds__(64, 4) void filter_gemv_kernel(
    const float* __restrict__ input,      // [N][D]
    const float* __restrict__ out2,       // [N]
    const float* __restrict__ emb,        // [K][D]
    float* __restrict__ max_partial,      // ws: [NBLK][K]
    float* __restrict__ out2_full)        // d_out + 7: [K][N]
{
    __shared__ float xl[ROWS_PER_BLK * XSTRIDE];  // 64 rows x 32 cols (padded)
    __shared__ float ws[KF * DT];                 // 7 x 32 weight chunk

    const int t   = threadIdx.x;          // 0..63 (one wave)
    const int r0  = blockIdx.x * ROWS_PER_BLK;
    const int row = r0 + t;

    const float* inp_base = input + (size_t)r0 * DDIM;

    float acc[KF];
#pragma unroll
    for (int k = 0; k < KF; ++k) acc[k] = 0.f;

    for (int dc = 0; dc < 2048; dc += DT) {
        // --- stage input tile: 64 rows x 32 cols, coalesced scalar loads ---
        // linear element e = i*64 + t ; r = e/32, c = e%32
        // consecutive lanes -> consecutive global addresses (128B per half-wave)
#pragma unroll
        for (int i = 0; i < DT; ++i) {
            int r = i * 2 + (t >> 5);
            int c = t & 31;
            xl[r * XSTRIDE + c] = inp_base[r * DDIM + dc + c];
        }
        // --- stage weight chunk: 7 x 32 ---
#pragma unroll
        for (int j = 0; j < 4; ++j) {
            int idx = j * 64 + t;
            if (idx < KF * DT) {
                int k = idx >> 5;
                int c = idx & 31;
                ws[k * DT + c] = emb[k * DDIM + dc + c];
            }
        }
        __syncthreads();

        // --- compute: each thread = its own row; weights are wave-uniform broadcasts ---
        const float4* xv = (const float4*)(xl + t * XSTRIDE);  // 144B-aligned
#pragma unroll
        for (int c4 = 0; c4 < DT / 4; ++c4) {
            float4 x = xv[c4];
#pragma unroll
            for (int k = 0; k < KF; ++k) {
                float4 w = ((const float4*)(ws + k * DT))[c4];
                acc[k] += x.x * w.x + x.y * w.y + x.z * w.z + x.w * w.w;
            }
        }
        __syncthreads();
    }

    // --- tail element d = 2048 (uniform emb addr -> scalar load; x uncoalesced but 1 elem/row) ---
    {
        float x = inp_base[t * DDIM + 2048];
#pragma unroll
        for (int k = 0; k < KF; ++k) acc[k] += x * emb[k * DDIM + 2048];
    }

    // --- epilogue: clip, write [7][N], wave-max partials ---
    float o2 = out2[row];
#pragma unroll
    for (int k = 0; k < KF; ++k) {
        float c = fminf(acc[k], o2);
        out2_full[k * N_ROWS + row] = c;   // coalesced across lanes
#pragma unroll
        for (int off = 32; off > 0; off >>= 1)
            c = fmaxf(c, __shfl_xor(c, off));
        if (t == 0) max_partial[blockIdx.x * KF + k] = c;
    }
}

// Stage 2: reduce per-block partial maxes -> d_out[0..6]
__global__ void max_reduce_kernel(const float* __restrict__ part,
                                  float* __restrict__ out)
{
    const int k = blockIdx.x;   // 0..6
    const int t = threadIdx.x;  // 0..255
    float m = -3.402823466e+38f;
    for (int i = t; i < NBLK; i += 256) m = fmaxf(m, part[i * KF + k]);
#pragma unroll
    for (int off = 32; off > 0; off >>= 1)
        m = fmaxf(m, __shfl_xor(m, off));
    __shared__ float red[4];
    if ((t & 63) == 0) red[t >> 6] = m;
    __syncthreads();
    if (t == 0) {
        m = fmaxf(fmaxf(red[0], red[1]), fmaxf(red[2], red[3]));
        out[k] = m;
    }
}

extern "C" void kernel_launch(void* const* d_in, const int* in_sizes, int n_in,
                              void* d_out, int out_size, void* d_ws, size_t ws_size,
                              hipStream_t stream) {
    const float* input = (const float*)d_in[0];   // [80000][2049] f32
    const float* out2  = (const float*)d_in[1];   // [80000] f32
    const float* emb   = (const float*)d_in[2];   // [7][2049] f32
    // d_in[3] = idx, ignored on the query=True path

    float* out  = (float*)d_out;                  // [0..6] maxes, [7..] clipped [7][N]
    float* part = (float*)d_ws;                   // [1250][7] partial maxes

    filter_gemv_kernel<<<NBLK, ROWS_PER_BLK, 0, stream>>>(
        input, out2, emb, part, out + KF);
    max_reduce_kernel<<<KF, 256, 0, stream>>>(part, out);
}